// Round 10
// baseline (1929.895 us; speedup 1.0000x reference)
//
#include <hip/hip_runtime.h>
#include <hip/hip_bf16.h>
#include <cstdint>
#include <cstddef>

#define DEV __device__ __forceinline__

// ---------------- problem constants ----------------
constexpr int BB    = 32;
constexpr int SEQ   = 1024;
constexpr int HID   = 1152;
constexpr int HEADS = 12;
constexpr int KVH   = 4;
constexpr int HD    = 96;
constexpr int KVC   = 384;   // KVH*HD
constexpr int MLPD  = 4608;
constexpr int ROWS  = BB * SEQ;          // 32768
constexpr int MODW  = 6 * HID;           // 6912

typedef __attribute__((ext_vector_type(8))) short short8;
typedef __attribute__((ext_vector_type(4))) float f32x4;

// ---------------- helpers ----------------
DEV float bfu2f(unsigned short u) {
    unsigned v = ((unsigned)u) << 16;
    return __builtin_bit_cast(float, v);
}
DEV unsigned short f2bf16u(float f) {
    unsigned u = __builtin_bit_cast(unsigned, f);
    u += 0x7FFFu + ((u >> 16) & 1u);   // RNE
    return (unsigned short)(u >> 16);
}
DEV unsigned pack2(float a, float b) {
    return (unsigned)f2bf16u(a) | ((unsigned)f2bf16u(b) << 16);
}
// gelu(tanh approx) = x * sigmoid(2z), 2z = 1.59576912*x + 0.071354814*x^3 (hw v_exp)
DEV float gelu_tanh(float x) {
    float x3 = x * x * x;
    float z2 = 1.59576912f * x + 0.071354814f * x3;
    return x / (1.f + __expf(-z2));
}

// async global->LDS, 16B per lane. LDS dest must be wave-uniform base (+lane*16).
DEV void gload16(const void* g, void* l) {
    __builtin_amdgcn_global_load_lds(
        (const __attribute__((address_space(1))) unsigned int*)g,
        (__attribute__((address_space(3))) unsigned int*)l,
        16, 0, 0);
}

// block reduce of two floats, blockDim.x == 256
DEV void block_reduce2(float& a, float& b) {
    #pragma unroll
    for (int off = 32; off > 0; off >>= 1) {
        a += __shfl_down(a, off, 64);
        b += __shfl_down(b, off, 64);
    }
    __shared__ float sa[4], sb[4];
    int w = threadIdx.x >> 6;
    if ((threadIdx.x & 63) == 0) { sa[w] = a; sb[w] = b; }
    __syncthreads();
    a = sa[0] + sa[1] + sa[2] + sa[3];
    b = sb[0] + sb[1] + sb[2] + sb[3];
    __syncthreads();
}

// ---------------- weight transpose + bf16 convert ----------------
__global__ void k_transpose_bf16(const float* __restrict__ in,
                                 unsigned short* __restrict__ out, int K, int N) {
    __shared__ float tile[32][33];
    int kb = blockIdx.x * 32;
    int nb = blockIdx.y * 32;
    int tx = threadIdx.x, ty = threadIdx.y;   // (32, 8)
    #pragma unroll
    for (int j = 0; j < 4; j++) {
        int k = kb + ty + j * 8;
        tile[ty + j * 8][tx] = (k < K && nb + tx < N) ? in[(size_t)k * N + nb + tx] : 0.f;
    }
    __syncthreads();
    #pragma unroll
    for (int j = 0; j < 4; j++) {
        int n = nb + ty + j * 8;
        if (n < N && kb + tx < K)
            out[(size_t)n * K + kb + tx] = f2bf16u(tile[tx][ty + j * 8]);
    }
}

// ---------------- adaLN: mod = silu(c) @ adaln_w + adaln_b ----------------
__global__ __launch_bounds__(256) void k_mod(const float* __restrict__ cvec,
                                             const float* __restrict__ w,
                                             const float* __restrict__ bias,
                                             float* __restrict__ mod) {
    const int col = blockIdx.x * 256 + threadIdx.x;
    const int bg = blockIdx.y * 8;
    __shared__ float sc[8][HID];
    for (int t = threadIdx.x; t < 8 * HID; t += 256) {
        int bb = t / HID, k = t % HID;
        float v = cvec[(bg + bb) * HID + k];
        sc[bb][k] = v / (1.f + __expf(-v));
    }
    __syncthreads();
    float acc[8];
    const float bv = bias[col];
    #pragma unroll
    for (int b = 0; b < 8; b++) acc[b] = bv;
    for (int k = 0; k < HID; k++) {
        float wv = w[(size_t)k * MODW + col];
        #pragma unroll
        for (int b = 0; b < 8; b++) acc[b] += sc[b][k] * wv;
    }
    #pragma unroll
    for (int b = 0; b < 8; b++) mod[(size_t)(bg + b) * MODW + col] = acc[b];
}

// ---------------- layernorm + modulate -> bf16 ----------------
__global__ __launch_bounds__(256) void k_ln_mod(const float* __restrict__ x,
                                                const float* __restrict__ mod,
                                                int shift_chunk, int scale_chunk,
                                                unsigned short* __restrict__ out,
                                                int r0) {
    const size_t row = blockIdx.x;
    const int b = (int)((r0 + row) >> 10);
    const float4* xr = (const float4*)(x + row * HID);
    const int t = threadIdx.x;
    float4 v0 = xr[t];
    float4 v1 = make_float4(0.f, 0.f, 0.f, 0.f);
    if (t < 32) v1 = xr[256 + t];
    float s  = v0.x + v0.y + v0.z + v0.w + v1.x + v1.y + v1.z + v1.w;
    float s2 = v0.x*v0.x + v0.y*v0.y + v0.z*v0.z + v0.w*v0.w
             + v1.x*v1.x + v1.y*v1.y + v1.z*v1.z + v1.w*v1.w;
    block_reduce2(s, s2);
    const float mean = s * (1.f / HID);
    float var = s2 * (1.f / HID) - mean * mean;
    const float rstd = rsqrtf(fmaxf(var, 0.f) + 1e-6f);
    const float* shiftp = mod + (size_t)b * MODW + shift_chunk * HID;
    const float* scalep = mod + (size_t)b * MODW + scale_chunk * HID;
    {
        float4 sc = *(const float4*)(scalep + 4 * t);
        float4 sh = *(const float4*)(shiftp + 4 * t);
        float y0 = ((v0.x - mean) * rstd) * (1.f + sc.x) + sh.x;
        float y1 = ((v0.y - mean) * rstd) * (1.f + sc.y) + sh.y;
        float y2 = ((v0.z - mean) * rstd) * (1.f + sc.z) + sh.z;
        float y3 = ((v0.w - mean) * rstd) * (1.f + sc.w) + sh.w;
        uint2 o; o.x = pack2(y0, y1); o.y = pack2(y2, y3);
        *(uint2*)(out + row * HID + 4 * t) = o;
    }
    if (t < 32) {
        int col = 1024 + 4 * t;
        float4 sc = *(const float4*)(scalep + col);
        float4 sh = *(const float4*)(shiftp + col);
        float y0 = ((v1.x - mean) * rstd) * (1.f + sc.x) + sh.x;
        float y1 = ((v1.y - mean) * rstd) * (1.f + sc.y) + sh.y;
        float y2 = ((v1.z - mean) * rstd) * (1.f + sc.z) + sh.z;
        float y3 = ((v1.w - mean) * rstd) * (1.f + sc.w) + sh.w;
        uint2 o; o.x = pack2(y0, y1); o.y = pack2(y2, y3);
        *(uint2*)(out + row * HID + col) = o;
    }
}

// ---------------- 128x128 bf16 MFMA GEMM, 2-phase double-buffered (T3 minimum recipe) ----------------
// Per K-tile: {issue next tile's 8 gload_lds -> OTHER buf; ds_read+MFMA current buf;
// __syncthreads (drains vmcnt/lgkmcnt)}. Loads get a full compute phase in flight.
// LDS 64KB -> 2 blocks/CU. Source-swizzled LDS (0 bank conflicts, verified r3-r8).
// __launch_bounds__(256,2): VGPR cap 256, acc 64+64 fits with huge margin (no r4 spill).
// EPI 1: out bf16 = gelu(acc+bias), NT store
// EPI 2: out fp32 = resid + gate[b,col]*(acc + bias)
// EPI 3: qkv split + fused focused-norm sums.
template <int EPI>
__global__ __launch_bounds__(256, 2) void k_gemm_bt(
        const unsigned short* __restrict__ A, const unsigned short* __restrict__ BT,
        const float* __restrict__ bias, const float* __restrict__ bias2,
        void* __restrict__ outp, void* __restrict__ out2,
        const float* __restrict__ resid, const float* __restrict__ gate,
        float* __restrict__ qsn, float* __restrict__ ksn,
        int Np, int K, int r0, int MBk, int GM, int GN, int XMg, int XNg) {
    __shared__ __align__(16) char As[32768];   // 2 x 16KB tile buffers
    __shared__ __align__(16) char Bs[32768];
    __shared__ float sb2[16], sb6[16];
    const int tid  = threadIdx.x;
    const int lane = tid & 63;
    const int wave = tid >> 6;
    const int wr = wave >> 1, wc = wave & 1;

    // supertile + 2D XCD sub-tile mapping (bijective)
    const int P  = GM * GN;
    const int s  = blockIdx.x / P;
    const int rr = blockIdx.x % P;
    const int xcd = rr & 7, off = rr >> 3;
    const int gm = GM / XMg, gn = GN / XNg;
    const int xm = xcd / XNg, xn = xcd % XNg;
    const int mloc = xm * gm + off / gn;
    const int nloc = xn * gn + off % gn;
    const int smCount = MBk / GM;
    const int sm = s % smCount, sn = s / smCount;
    const int m0 = (sm * GM + mloc) << 7;
    const int n0 = (sn * GN + nloc) << 7;

    // staging: wave w covers rows 32w..32w+31 (4 chunks of 8 rows = 1KB each).
    const int srow = lane >> 3;
    const int kgrp = (lane & 7) ^ srow;
    const unsigned short* aS = A  + (size_t)(m0 + 32 * wave + srow) * K + kgrp * 8;
    const unsigned short* bS = BT + (size_t)(n0 + 32 * wave + srow) * K + kgrp * 8;
    const size_t chunkK = (size_t)8 * K;
    const int dwo = wave * 4096;

    // fragment read offsets: byte = r*128 + ((kg ^ (r&7))<<4); kk=1 -> ^64
    const int hi = lane >> 4;
    const int lo = lane & 15;
    const int swz = ((hi ^ (lo & 7)) << 4);
    int aoff[4], boff[4];
    #pragma unroll
    for (int i = 0; i < 4; i++) {
        aoff[i] = (wr * 64 + i * 16 + lo) * 128 + swz;
        boff[i] = (wc * 64 + i * 16 + lo) * 128 + swz;
    }

    f32x4 acc[4][4];
    #pragma unroll
    for (int i = 0; i < 4; i++)
        #pragma unroll
        for (int j = 0; j < 4; j++)
            acc[i][j] = (f32x4){0.f, 0.f, 0.f, 0.f};

    if constexpr (EPI == 3) {
        if (tid < 16) { sb2[tid] = 0.f; sb6[tid] = 0.f; }
    }

    auto compute = [&](const char* Ab, const char* Bb) {
        __builtin_amdgcn_s_setprio(1);
        #pragma unroll
        for (int kk = 0; kk < 2; kk++) {
            const int kx = kk << 6;
            short8 bfr[4];
            #pragma unroll
            for (int j = 0; j < 4; j++)
                bfr[j] = *(const short8*)(Bb + (boff[j] ^ kx));
            #pragma unroll
            for (int i = 0; i < 4; i++) {
                short8 af = *(const short8*)(Ab + (aoff[i] ^ kx));
                #pragma unroll
                for (int j = 0; j < 4; j++)
                    acc[i][j] = __builtin_amdgcn_mfma_f32_16x16x32_bf16(af, bfr[j], acc[i][j], 0, 0, 0);
            }
        }
        __builtin_amdgcn_s_setprio(0);
    };

    const int nk = K >> 6;                 // K = 1152 or 4608 -> nk even (18 / 72)
    // prologue: tile 0 -> buf 0
    #pragma unroll
    for (int j = 0; j < 4; j++) {
        gload16(aS + j * chunkK, As + dwo + j * 1024);
        gload16(bS + j * chunkK, Bs + dwo + j * 1024);
    }
    aS += 64; bS += 64;
    __syncthreads();

    for (int kt = 0; kt < nk; kt += 2) {
        // phase A: stage tile kt+1 -> buf1 (kt+1 < nk always, nk even), compute buf0
        #pragma unroll
        for (int j = 0; j < 4; j++) {
            gload16(aS + j * chunkK, As + 16384 + dwo + j * 1024);
            gload16(bS + j * chunkK, Bs + 16384 + dwo + j * 1024);
        }
        aS += 64; bS += 64;
        compute(As, Bs);
        __syncthreads();
        // phase B: stage tile kt+2 -> buf0 (if any), compute buf1
        if (kt + 2 < nk) {
            #pragma unroll
            for (int j = 0; j < 4; j++) {
                gload16(aS + j * chunkK, As + dwo + j * 1024);
                gload16(bS + j * chunkK, Bs + dwo + j * 1024);
            }
            aS += 64; bS += 64;
        }
        compute(As + 16384, Bs + 16384);
        __syncthreads();
    }

    // epilogue. C/D layout: col = lane&15, row = 4*(lane>>4)+reg
    const int c_l = lane & 15;
    const int r_l = (lane >> 4) << 2;
    #pragma unroll
    for (int j = 0; j < 4; j++) {
        const int fcol = n0 + wc * 64 + j * 16 + c_l;
        float bvv;
        if constexpr (EPI == 3) bvv = (fcol < HID) ? bias[fcol] : bias2[fcol - HID];
        else                    bvv = bias[fcol];
        float s2l = 0.f, s6l = 0.f;
        #pragma unroll
        for (int i = 0; i < 4; i++) {
            const int frow = m0 + wr * 64 + i * 16 + r_l;
            #pragma unroll
            for (int r = 0; r < 4; r++) {
                float v = acc[i][j][r] + bvv;
                if constexpr (EPI == 1) {
                    __builtin_nontemporal_store(f2bf16u(gelu_tanh(v)),
                        (unsigned short*)outp + (size_t)(frow + r) * Np + fcol);
                } else if constexpr (EPI == 2) {
                    const size_t off2 = (size_t)(frow + r) * Np + fcol;
                    const int bb = (r0 + frow + r) >> 10;
                    ((float*)outp)[off2] = resid[off2] + gate[(size_t)bb * MODW + fcol] * v;
                } else {  // EPI 3
                    unsigned short bf = f2bf16u(v);
                    if (fcol < HID) ((unsigned short*)outp)[(size_t)(frow + r) * HID + fcol] = bf;
                    else            ((unsigned short*)out2)[(size_t)(frow + r) * (2*KVC) + (fcol - HID)] = bf;
                    if (fcol < HID + KVC) {
                        float rv = fmaxf(v, 0.f);
                        float v2 = rv * rv;
                        s2l += v2;
                        s6l += v2 * v2 * v2;
                    }
                }
            }
        }
        if constexpr (EPI == 3) {
            if (fcol < HID + KVC) {
                s2l += __shfl_down(s2l, 32, 64); s2l += __shfl_down(s2l, 16, 64);
                s6l += __shfl_down(s6l, 32, 64); s6l += __shfl_down(s6l, 16, 64);
                if (lane < 16) {
                    const int slot = (fcol < HID) ? (fcol / 96) : (12 + (fcol - HID) / 96);
                    atomicAdd(&sb2[slot], s2l);
                    atomicAdd(&sb6[slot], s6l);
                }
            }
        }
    }
    if constexpr (EPI == 3) {
        __syncthreads();
        if (tid < 16) {
            const int b = (r0 + m0) >> 10;
            if (tid < 12) {
                atomicAdd(&qsn[(b * HEADS + tid) * 2],     sb2[tid]);
                atomicAdd(&qsn[(b * HEADS + tid) * 2 + 1], sb6[tid]);
            } else {
                atomicAdd(&ksn[(b * KVH + tid - 12) * 2],     sb2[tid]);
                atomicAdd(&ksn[(b * KVH + tid - 12) * 2 + 1], sb6[tid]);
            }
        }
    }
}

// ---------------- finisher: norm sums -> scales (1 block, 512 threads) ----------------
__global__ void k_fin(const float* __restrict__ qsn, const float* __restrict__ ksn,
                      float* __restrict__ qsc, float* __restrict__ ksc) {
    const int t = threadIdx.x;
    if (t < BB * HEADS) {
        float s2 = qsn[t * 2], s6 = qsn[t * 2 + 1];
        float apn = (s6 == 0.f) ? 1e-12f : sqrtf(s6);
        qsc[t] = sqrtf(s2) / apn;
    } else if (t < BB * HEADS + BB * KVH) {
        int i = t - BB * HEADS;
        float s2 = ksn[i * 2], s6 = ksn[i * 2 + 1];
        float apn = (s6 == 0.f) ? 1e-12f : sqrtf(s6);
        ksc[i] = sqrtf(s2) / apn;
    }
}

// ---------------- depthwise 3x3 conv (bf16 in): 4 channels/thread ----------------
__global__ __launch_bounds__(256) void k_dwconv(const unsigned short* __restrict__ kvl,
                                                const float* __restrict__ w,
                                                const float* __restrict__ bias,
                                                unsigned short* __restrict__ vd) {
    const int idx = blockIdx.x * 256 + threadIdx.x;   // < CROWS*96
    const int c4 = idx % 96;
    const int bn = idx / 96;
    const int n = bn & 1023;
    const int b = bn >> 10;
    const int y = n >> 5, xx = n & 31;
    float4 acc = *(const float4*)(bias + c4 * 4);
    #pragma unroll
    for (int dy = -1; dy <= 1; dy++) {
        const int yy = y + dy;
        if ((unsigned)yy > 31u) continue;
        #pragma unroll
        for (int dx = -1; dx <= 1; dx++) {
            const int xc = xx + dx;
            if ((unsigned)xc > 31u) continue;
            uint2 u = *(const uint2*)(kvl + ((size_t)b * SEQ + yy * 32 + xc) * (2*KVC) + KVC + c4 * 4);
            const int t = (dy + 1) * 3 + (dx + 1);
            acc.x += w[(c4 * 4 + 0) * 9 + t] * bfu2f((unsigned short)(u.x & 0xffff));
            acc.y += w[(c4 * 4 + 1) * 9 + t] * bfu2f((unsigned short)(u.x >> 16));
            acc.z += w[(c4 * 4 + 2) * 9 + t] * bfu2f((unsigned short)(u.y & 0xffff));
            acc.w += w[(c4 * 4 + 3) * 9 + t] * bfu2f((unsigned short)(u.y >> 16));
        }
    }
    uint2 o; o.x = pack2(acc.x, acc.y); o.y = pack2(acc.z, acc.w);
    *(uint2*)(vd + (size_t)idx * 4) = o;
}

// ---------------- kvmat partials: relu(k)^3 ^T @ v over 128-row chunk ----------------
__global__ __launch_bounds__(256) void k_kvpart(const unsigned short* __restrict__ kvl,
                                                float* __restrict__ kvmp) {
    const int chunk = blockIdx.x & 7;
    const int bh = blockIdx.x >> 3;
    const int b = bh >> 2, h = bh & 3;
    __shared__ float Ks[16][96], Vs[16][96];
    float acc[6][6];
    #pragma unroll
    for (int i = 0; i < 6; i++)
        #pragma unroll
        for (int j = 0; j < 6; j++) acc[i][j] = 0.f;
    const int ti = threadIdx.x >> 4, tj = threadIdx.x & 15;
    const unsigned short* kbase = kvl + ((size_t)b * SEQ + chunk * 128) * (2*KVC) + h * HD;
    for (int n0 = 0; n0 < 128; n0 += 16) {
        __syncthreads();
        for (int i = threadIdx.x; i < 384; i += 256) {
            const int kv = (i >= 192);
            const int j = i - kv * 192;
            const int row = j / 12, c = j % 12;
            uint4 u = *(const uint4*)(kbase + (size_t)(n0 + row) * (2*KVC) + kv * KVC + c * 8);
            const unsigned short* e = (const unsigned short*)&u;
            if (!kv) {
                #pragma unroll
                for (int q = 0; q < 8; q++) {
                    float r = fmaxf(bfu2f(e[q]), 0.f);
                    Ks[row][c * 8 + q] = r * r * r;
                }
            } else {
                #pragma unroll
                for (int q = 0; q < 8; q++) Vs[row][c * 8 + q] = bfu2f(e[q]);
            }
        }
        __syncthreads();
        for (int nn = 0; nn < 16; nn++) {
            float av[6], bv[6];
            #pragma unroll
            for (int i = 0; i < 6; i++) av[i] = Ks[nn][ti * 6 + i];
            #pragma unroll
            for (int j = 0; j < 6; j++) bv[j] = Vs[nn][tj * 6 + j];
            #pragma unroll
            for (int i = 0; i < 6; i++)
                #pragma unroll
                for (int j = 0; j < 6; j++) acc[i][j] += av[i] * bv[j];
        }
    }
    float* out = kvmp + ((size_t)bh * 8 + chunk) * 9216;
    #pragma unroll
    for (int i = 0; i < 6; i++)
        #pragma unroll
        for (int j = 0; j < 6; j++)
            out[(size_t)(ti * 6 + i) * 96 + tj * 6 + j] = acc[i][j];
}

// ---------------- kvmat reduce: sum 8 partials, apply kscale, emit TRANSPOSED bf16 ----------------
__global__ __launch_bounds__(256) void k_kvred(const float* __restrict__ kvmp,
                                               const float* __restrict__ ksc,
                                               unsigned short* __restrict__ kvmT, int b0) {
    const int idx = blockIdx.x * 256 + threadIdx.x;   // < CB*4*9216
    const int bh = idx / 9216;
    const int i  = idx % 9216;                        // i = d*96 + e
    float s = 0.f;
    #pragma unroll
    for (int c = 0; c < 8; c++) s += kvmp[((size_t)bh * 8 + c) * 9216 + i];
    s *= ksc[(b0 + (bh >> 2)) * KVH + (bh & 3)];
    const int d = i / 96, e = i % 96;
    kvmT[(size_t)bh * 9216 + e * 96 + d] = f2bf16u(s);
}

// ---------------- o = focused(q) @ kvmat[h%4] + vd[h%4] -- MFMA version ----------------
__global__ __launch_bounds__(256) void k_ogemm(const unsigned short* __restrict__ ql,
                                               const float* __restrict__ qscale,
                                               const unsigned short* __restrict__ kvmT,
                                               const unsigned short* __restrict__ vd,
                                               unsigned short* __restrict__ obuf,
                                               int b0) {
    const int rc = blockIdx.x;   // 0..7 row chunks of 128
    const int h  = blockIdx.y;   // 0..11
    const int b  = blockIdx.z;   // local batch
    const int kvh = h & 3;
    __shared__ unsigned short Qs[128][104];
    __shared__ unsigned short Ms[96][104];
    const int tid = threadIdx.x;
    const float qs = qscale[(b0 + b) * HEADS + h];
    const unsigned short* mt = kvmT + (size_t)(b * KVH + kvh) * 9216;
    for (int i = tid; i < 1152; i += 256) {
        const int row = i / 12, c = i % 12;
        *(uint4*)&Ms[row][c * 8] = *(const uint4*)(mt + row * 96 + c * 8);
    }
    const unsigned short* qb = ql + ((size_t)(b * SEQ + rc * 128)) * HID + h * HD;
    for (int i = tid; i < 1536; i += 256) {
        const int row = i / 12, c = i % 12;
        uint4 u = *(const uint4*)(qb + (size_t)row * HID + c * 8);
        const unsigned short* e = (const unsigned short*)&u;
        unsigned short o8[8];
        #pragma unroll
        for (int q = 0; q < 8; q++) {
            float a = fmaxf(bfu2f(e[q]), 0.f);
            o8[q] = f2bf16u(qs * a * a * a);
        }
        *(uint4*)&Qs[row][c * 8] = *(uint4*)o8;
    }
    __syncthreads();
    const int wave = tid >> 6, lane = tid & 63;
    const int lo = lane & 15, hi = lane >> 4;
    f32x4 acc[2][6];
    #pragma unroll
    for (int m = 0; m < 2; m++)
        #pragma unroll
        for (int n = 0; n < 6; n++) acc[m][n] = (f32x4){0.f, 0.f, 0.f, 0.f};
    #pragma unroll
    for (int ks = 0; ks < 3; ks++) {
        short8 af[2], bf[6];
        #pragma unroll
        for (int m = 0; m < 2; m++)
            af[m] = *(const short8*)&Qs[wave * 32 + m * 16 + lo][ks * 32 + 8 * hi];
        #pragma unroll
        for (int n = 0; n < 6; n++)
            bf[n] = *(const short8*)&Ms[n * 16 + lo][ks * 32 + 8 * hi];
        #pragma unroll
        for (int m = 0; m < 2; m++)
            #pragma unroll
            for (int n = 0; n < 6; n++)
                acc[m][n] = __builtin_amdgcn_mfma_f32_16x16x32_bf16(af[m], bf[n], acc[m][n], 0, 0, 0);
    }
    #pragma unroll
    for (int m = 0; m < 2; m++) {
        #pragma unroll
        for (int n = 0; n < 6; n++) {
            const int e = n * 16 + lo;
            #pragma unroll
            for (int r = 0; r < 4; r++) {
                const size_t gr = (size_t)b * SEQ + rc * 128 + wave * 32 + m * 16 + 4 * hi + r;
                float v = acc[m][n][r] + bfu2f(vd[gr * KVC + kvh * HD + e]);
                obuf[gr * HID + h * HD + e] = f2bf16u(v);
            }
        }
    }
}

// ---------------- fixed workspace layout ----------------
constexpr size_t WQKV_OFF = 0;                                    // [1920][1152] bf16
constexpr size_t WPT_OFF  = WQKV_OFF + (size_t)1920*1152*2;       // [1152][1152] bf16
constexpr size_t W1T_OFF  = WPT_OFF  + (size_t)1152*1152*2;       // [4608][1152] bf16
constexpr size_t W2T_OFF  = W1T_OFF  + (size_t)4608*1152*2;       // [1152][4608] bf16
constexpr size_t MOD_OFF  = W2T_OFF  + (size_t)1152*4608*2;       // 32*6912 f32
constexpr size_t QSN_OFF  = MOD_OFF  + (size_t)BB*MODW*4;         // 32*12*2 f32 (s2,s6)
constexpr size_t KSN_OFF  = QSN_OFF  + (size_t)BB*HEADS*2*4;      // 32*4*2 f32
constexpr size_t QSC_OFF  = KSN_OFF  + (size_t)BB*KVH*2*4;        // 32*12 f32
constexpr size_t KSC_OFF  = QSC_OFF  + (size_t)BB*HEADS*4;        // 32*4 f32
constexpr size_t DYN_OFF  = KSC_OFF  + (size_t)BB*KVH*4;          // chunked scratch

extern "C" void kernel_launch(void* const* d_in, const int* in_sizes, int n_in,
                              void* d_out, int out_size, void* d_ws, size_t ws_size,
                              hipStream_t stream) {
    (void)in_sizes; (void)n_in; (void)out_size;

    const float* x       = (const float*)d_in[0];
    const float* cvec    = (const float*)d_in[1];
    const float* wq_w    = (const float*)d_in[2];
    const float* wq_b    = (const float*)d_in[3];
    const float* wkv_w   = (const float*)d_in[4];
    const float* wkv_b   = (const float*)d_in[5];
    const float* dwc_w   = (const float*)d_in[6];
    const float* dwc_b   = (const float*)d_in[7];
    const float* proj_w  = (const float*)d_in[8];
    const float* proj_b  = (const float*)d_in[9];
    const float* adaln_w = (const float*)d_in[10];
    const float* adaln_b = (const float*)d_in[11];
    const float* mlp_w1  = (const float*)d_in[12];
    const float* mlp_b1  = (const float*)d_in[13];
    const float* mlp_w2  = (const float*)d_in[14];
    const float* mlp_b2  = (const float*)d_in[15];

    // ---- adaptive chunk size ----
    int CB = 0;
    for (int cb = 32; cb >= 1; cb >>= 1) {
        size_t rows = (size_t)cb * 1024;
        size_t attn = rows * (1152*2 + 1152*2 + 768*2 + 384*2 + 1152*2)
                    + (size_t)cb * (4*8*9216*4 /*KVMp*/ + 4*9216*2 /*KVMT*/);
        size_t mlp  = rows * (1152*2 + 4608*2);
        size_t need = DYN_OFF + (attn > mlp ? attn : mlp);
        if (need <= ws_size) { CB = cb; break; }
    }
    if (CB == 0) return;
    const size_t CROWS = (size_t)CB * 1024;

    char* ws = (char*)d_ws;
    unsigned short* WQKV = (unsigned short*)(ws + WQKV_OFF);
    unsigned short* WPT  = (unsigned short*)(ws + WPT_OFF);
    unsigned short* W1T  = (unsigned short*)(ws + W1T_OFF);
    unsigned short* W2T  = (unsigned short*)(ws + W2T_OFF);
    float*          MODp = (float*)(ws + MOD_OFF);
    float*          QSN  = (float*)(ws + QSN_OFF);
    float*          KSN  = (float*)(ws + KSN_OFF);
    float*          QSC  = (float*)(ws + QSC_OFF);
    float*          KSC  = (float*)(ws + KSC_OFF);
    char* dyn = ws + DYN_OFF;
    unsigned short* XMc  = (unsigned short*)dyn;
    unsigned short* QLc  = (unsigned short*)(dyn + CROWS * 1152 * 2);
    unsigned short* KVLc = (unsigned short*)((char*)QLc + CROWS * 1152 * 2);
    float*          KVMp = (float*)((char*)KVLc + CROWS * 768 * 2);
    unsigned short* KVMT = (unsigned short*)((char*)KVMp + (size_t)CB * 4 * 8 * 9216 * 4);
    unsigned short* VDc  = (unsigned short*)((char*)KVMT + (size_t)CB * 4 * 9216 * 2);
    unsigned short* OBc  = (unsigned short*)((char*)VDc + CROWS * 384 * 2);
    unsigned short* XM2  = (unsigned short*)dyn;
    unsigned short* Hc   = (unsigned short*)(dyn + CROWS * 1152 * 2);
    float*          OUT  = (float*)d_out;

    dim3 tb(32, 8);
    k_transpose_bf16<<<dim3(36, 36),  tb, 0, stream>>>(wq_w,   WQKV,             1152, 1152);
    k_transpose_bf16<<<dim3(36, 24),  tb, 0, stream>>>(wkv_w,  WQKV + 1152*1152, 1152, 768);
    k_transpose_bf16<<<dim3(36, 36),  tb, 0, stream>>>(proj_w, WPT,              1152, 1152);
    k_transpose_bf16<<<dim3(36, 144), tb, 0, stream>>>(mlp_w1, W1T,              1152, 4608);
    k_transpose_bf16<<<dim3(144, 36), tb, 0, stream>>>(mlp_w2, W2T,              4608, 1152);

    k_mod<<<dim3(27, 4), 256, 0, stream>>>(cvec, adaln_w, adaln_b, MODp);
    hipMemsetAsync(ws + QSN_OFF, 0, (size_t)(BB*HEADS*2 + BB*KVH*2) * 4, stream);

    const int MB = (int)(CROWS >> 7);      // 128-row M blocks per chunk
    const int GM = MB < 16 ? MB : 16;

    // --- attention branch, chunked over batches ---
    for (int b0 = 0; b0 < BB; b0 += CB) {
        const int r0 = b0 << 10;
        const float* xch = x + (size_t)r0 * HID;
        k_ln_mod<<<(int)CROWS, 256, 0, stream>>>(xch, MODp, 0, 1, XMc, r0);
        k_gemm_bt<3><<<15 * MB, 256, 0, stream>>>(XMc, WQKV, wq_b, wkv_b, QLc, KVLc,
                                                  nullptr, nullptr, QSN, KSN,
                                                  0, 1152, r0, MB, GM, 5, 8, 1);
        k_dwconv<<<(int)(CROWS * 96 / 256), 256, 0, stream>>>(KVLc, dwc_w, dwc_b, VDc);
        k_kvpart<<<CB * 4 * 8, 256, 0, stream>>>(KVLc, KVMp);
        k_fin<<<1, 512, 0, stream>>>(QSN, KSN, QSC, KSC);
        k_kvred<<<CB * 144, 256, 0, stream>>>(KVMp, KSC, KVMT, b0);
        k_ogemm<<<dim3(8, HEADS, CB), 256, 0, stream>>>(QLc, QSC, KVMT, VDc, OBc, b0);
        k_gemm_bt<2><<<9 * MB, 256, 0, stream>>>(OBc, WPT, proj_b, nullptr, OUT + (size_t)r0 * HID, nullptr,
                                                 xch, MODp + 2 * HID, nullptr, nullptr,
                                                 1152, 1152, r0, MB, GM, 9, 8, 1);
    }

    // --- MLP branch, chunked over rows (d_out now holds x1 = x + gate*attn) ---
    for (int r0 = 0; r0 < ROWS; r0 += (int)CROWS) {
        float* x1ch = OUT + (size_t)r0 * HID;
        k_ln_mod<<<(int)CROWS, 256, 0, stream>>>(x1ch, MODp, 3, 4, XM2, r0);
        k_gemm_bt<1><<<36 * MB, 256, 0, stream>>>(XM2, W1T, mlp_b1, nullptr, Hc, nullptr,
                                                  nullptr, nullptr, nullptr, nullptr,
                                                  4608, 1152, 0, MB, GM, 12, 2, 4);
        k_gemm_bt<2><<<9 * MB, 256, 0, stream>>>(Hc, W2T, mlp_b2, nullptr, x1ch, nullptr,
                                                 x1ch, MODp + 5 * HID, nullptr, nullptr,
                                                 1152, 4608, r0, MB, GM, 9, 8, 1);
    }
}

// Round 11
// 1873.018 us; speedup vs baseline: 1.0304x; 1.0304x over previous
//
#include <hip/hip_runtime.h>
#include <hip/hip_bf16.h>
#include <cstdint>
#include <cstddef>

#define DEV __device__ __forceinline__

// ---------------- problem constants ----------------
constexpr int BB    = 32;
constexpr int SEQ   = 1024;
constexpr int HID   = 1152;
constexpr int HEADS = 12;
constexpr int KVH   = 4;
constexpr int HD    = 96;
constexpr int KVC   = 384;   // KVH*HD
constexpr int MLPD  = 4608;
constexpr int ROWS  = BB * SEQ;          // 32768
constexpr int MODW  = 6 * HID;           // 6912

typedef __attribute__((ext_vector_type(8))) short short8;
typedef __attribute__((ext_vector_type(4))) float f32x4;

// ---------------- helpers ----------------
DEV float bfu2f(unsigned short u) {
    unsigned v = ((unsigned)u) << 16;
    return __builtin_bit_cast(float, v);
}
DEV unsigned short f2bf16u(float f) {
    unsigned u = __builtin_bit_cast(unsigned, f);
    u += 0x7FFFu + ((u >> 16) & 1u);   // RNE
    return (unsigned short)(u >> 16);
}
DEV unsigned pack2(float a, float b) {
    return (unsigned)f2bf16u(a) | ((unsigned)f2bf16u(b) << 16);
}
// gelu(tanh approx) = x * sigmoid(2z), 2z = 1.59576912*x + 0.071354814*x^3 (hw v_exp)
DEV float gelu_tanh(float x) {
    float x3 = x * x * x;
    float z2 = 1.59576912f * x + 0.071354814f * x3;
    return x / (1.f + __expf(-z2));
}

// async global->LDS, 16B per lane. LDS dest must be wave-uniform base (+lane*16).
DEV void gload16(const void* g, void* l) {
    __builtin_amdgcn_global_load_lds(
        (const __attribute__((address_space(1))) unsigned int*)g,
        (__attribute__((address_space(3))) unsigned int*)l,
        16, 0, 0);
}

// block reduce of two floats, blockDim.x == 256
DEV void block_reduce2(float& a, float& b) {
    #pragma unroll
    for (int off = 32; off > 0; off >>= 1) {
        a += __shfl_down(a, off, 64);
        b += __shfl_down(b, off, 64);
    }
    __shared__ float sa[4], sb[4];
    int w = threadIdx.x >> 6;
    if ((threadIdx.x & 63) == 0) { sa[w] = a; sb[w] = b; }
    __syncthreads();
    a = sa[0] + sa[1] + sa[2] + sa[3];
    b = sb[0] + sb[1] + sb[2] + sb[3];
    __syncthreads();
}

// ---------------- weight transpose + bf16 convert ----------------
__global__ void k_transpose_bf16(const float* __restrict__ in,
                                 unsigned short* __restrict__ out, int K, int N) {
    __shared__ float tile[32][33];
    int kb = blockIdx.x * 32;
    int nb = blockIdx.y * 32;
    int tx = threadIdx.x, ty = threadIdx.y;   // (32, 8)
    #pragma unroll
    for (int j = 0; j < 4; j++) {
        int k = kb + ty + j * 8;
        tile[ty + j * 8][tx] = (k < K && nb + tx < N) ? in[(size_t)k * N + nb + tx] : 0.f;
    }
    __syncthreads();
    #pragma unroll
    for (int j = 0; j < 4; j++) {
        int n = nb + ty + j * 8;
        if (n < N && kb + tx < K)
            out[(size_t)n * K + kb + tx] = f2bf16u(tile[tx][ty + j * 8]);
    }
}

// ---------------- adaLN: mod = silu(c) @ adaln_w + adaln_b ----------------
__global__ __launch_bounds__(256) void k_mod(const float* __restrict__ cvec,
                                             const float* __restrict__ w,
                                             const float* __restrict__ bias,
                                             float* __restrict__ mod) {
    const int col = blockIdx.x * 256 + threadIdx.x;
    const int bg = blockIdx.y * 8;
    __shared__ float sc[8][HID];
    for (int t = threadIdx.x; t < 8 * HID; t += 256) {
        int bb = t / HID, k = t % HID;
        float v = cvec[(bg + bb) * HID + k];
        sc[bb][k] = v / (1.f + __expf(-v));
    }
    __syncthreads();
    float acc[8];
    const float bv = bias[col];
    #pragma unroll
    for (int b = 0; b < 8; b++) acc[b] = bv;
    for (int k = 0; k < HID; k++) {
        float wv = w[(size_t)k * MODW + col];
        #pragma unroll
        for (int b = 0; b < 8; b++) acc[b] += sc[b][k] * wv;
    }
    #pragma unroll
    for (int b = 0; b < 8; b++) mod[(size_t)(bg + b) * MODW + col] = acc[b];
}

// ---------------- layernorm + modulate -> bf16 ----------------
__global__ __launch_bounds__(256) void k_ln_mod(const float* __restrict__ x,
                                                const float* __restrict__ mod,
                                                int shift_chunk, int scale_chunk,
                                                unsigned short* __restrict__ out,
                                                int r0) {
    const size_t row = blockIdx.x;
    const int b = (int)((r0 + row) >> 10);
    const float4* xr = (const float4*)(x + row * HID);
    const int t = threadIdx.x;
    float4 v0 = xr[t];
    float4 v1 = make_float4(0.f, 0.f, 0.f, 0.f);
    if (t < 32) v1 = xr[256 + t];
    float s  = v0.x + v0.y + v0.z + v0.w + v1.x + v1.y + v1.z + v1.w;
    float s2 = v0.x*v0.x + v0.y*v0.y + v0.z*v0.z + v0.w*v0.w
             + v1.x*v1.x + v1.y*v1.y + v1.z*v1.z + v1.w*v1.w;
    block_reduce2(s, s2);
    const float mean = s * (1.f / HID);
    float var = s2 * (1.f / HID) - mean * mean;
    const float rstd = rsqrtf(fmaxf(var, 0.f) + 1e-6f);
    const float* shiftp = mod + (size_t)b * MODW + shift_chunk * HID;
    const float* scalep = mod + (size_t)b * MODW + scale_chunk * HID;
    {
        float4 sc = *(const float4*)(scalep + 4 * t);
        float4 sh = *(const float4*)(shiftp + 4 * t);
        float y0 = ((v0.x - mean) * rstd) * (1.f + sc.x) + sh.x;
        float y1 = ((v0.y - mean) * rstd) * (1.f + sc.y) + sh.y;
        float y2 = ((v0.z - mean) * rstd) * (1.f + sc.z) + sh.z;
        float y3 = ((v0.w - mean) * rstd) * (1.f + sc.w) + sh.w;
        uint2 o; o.x = pack2(y0, y1); o.y = pack2(y2, y3);
        *(uint2*)(out + row * HID + 4 * t) = o;
    }
    if (t < 32) {
        int col = 1024 + 4 * t;
        float4 sc = *(const float4*)(scalep + col);
        float4 sh = *(const float4*)(shiftp + col);
        float y0 = ((v1.x - mean) * rstd) * (1.f + sc.x) + sh.x;
        float y1 = ((v1.y - mean) * rstd) * (1.f + sc.y) + sh.y;
        float y2 = ((v1.z - mean) * rstd) * (1.f + sc.z) + sh.z;
        float y3 = ((v1.w - mean) * rstd) * (1.f + sc.w) + sh.w;
        uint2 o; o.x = pack2(y0, y1); o.y = pack2(y2, y3);
        *(uint2*)(out + row * HID + col) = o;
    }
}

// ---------------- 128x128 bf16 MFMA GEMM (r8-proven 2-barrier structure) ----------------
// 32KB LDS -> 4 blocks/CU of TLP; this beats every intra-block pipeline tried (r6/r9/r10).
// __launch_bounds__(256,4): 64 VGPR + 64 AGPR = 128/wave exactly; (256,5) SPILLS (r4).
// EPI 1: out bf16 = gelu(acc + bias), NT store
// EPI 2: out fp32 = resid + gate[b,col]*(acc + bias)
// EPI 3: qkv split + fused focused-norm sums.
template <int EPI>
__global__ __launch_bounds__(256, 4) void k_gemm_bt(
        const unsigned short* __restrict__ A, const unsigned short* __restrict__ BT,
        const float* __restrict__ bias, const float* __restrict__ bias2,
        void* __restrict__ outp, void* __restrict__ out2,
        const float* __restrict__ resid, const float* __restrict__ gate,
        float* __restrict__ qsn, float* __restrict__ ksn,
        int Np, int K, int r0, int MBk, int GM, int GN, int XMg, int XNg) {
    __shared__ __align__(16) char As[16384];
    __shared__ __align__(16) char Bs[16384];
    __shared__ float sb2[16], sb6[16];
    const int tid  = threadIdx.x;
    const int lane = tid & 63;
    const int wave = tid >> 6;
    const int wr = wave >> 1, wc = wave & 1;

    // supertile + 2D XCD sub-tile mapping (bijective)
    const int P  = GM * GN;
    const int s  = blockIdx.x / P;
    const int rr = blockIdx.x % P;
    const int xcd = rr & 7, off = rr >> 3;
    const int gm = GM / XMg, gn = GN / XNg;
    const int xm = xcd / XNg, xn = xcd % XNg;
    const int mloc = xm * gm + off / gn;
    const int nloc = xn * gn + off % gn;
    const int smCount = MBk / GM;
    const int sm = s % smCount, sn = s / smCount;
    const int m0 = (sm * GM + mloc) << 7;
    const int n0 = (sn * GN + nloc) << 7;

    // staging: wave w covers rows 32w..32w+31 (4 chunks of 8 rows = 1KB each).
    const int srow = lane >> 3;
    const int kgrp = (lane & 7) ^ srow;
    const unsigned short* aS = A  + (size_t)(m0 + 32 * wave + srow) * K + kgrp * 8;
    const unsigned short* bS = BT + (size_t)(n0 + 32 * wave + srow) * K + kgrp * 8;
    const size_t chunkK = (size_t)8 * K;
    char* aD = As + wave * 4096;
    char* bD = Bs + wave * 4096;

    // fragment read offsets: byte = r*128 + ((kg ^ (r&7))<<4); kk=1 -> ^64
    const int hi = lane >> 4;
    const int lo = lane & 15;
    const int swz = ((hi ^ (lo & 7)) << 4);
    int aoff[4], boff[4];
    #pragma unroll
    for (int i = 0; i < 4; i++) {
        aoff[i] = (wr * 64 + i * 16 + lo) * 128 + swz;
        boff[i] = (wc * 64 + i * 16 + lo) * 128 + swz;
    }

    f32x4 acc[4][4];
    #pragma unroll
    for (int i = 0; i < 4; i++)
        #pragma unroll
        for (int j = 0; j < 4; j++)
            acc[i][j] = (f32x4){0.f, 0.f, 0.f, 0.f};

    if constexpr (EPI == 3) {
        if (tid < 16) { sb2[tid] = 0.f; sb6[tid] = 0.f; }
    }

    const int nk = K >> 6;
    for (int kt = 0; kt < nk; ++kt) {
        __syncthreads();
        #pragma unroll
        for (int j = 0; j < 4; j++) {
            gload16(aS + j * chunkK, aD + j * 1024);
            gload16(bS + j * chunkK, bD + j * 1024);
        }
        aS += 64; bS += 64;
        __syncthreads();
        #pragma unroll
        for (int kk = 0; kk < 2; kk++) {
            const int kx = kk << 6;
            short8 bfr[4];
            #pragma unroll
            for (int j = 0; j < 4; j++)
                bfr[j] = *(const short8*)(Bs + (boff[j] ^ kx));
            #pragma unroll
            for (int i = 0; i < 4; i++) {
                short8 af = *(const short8*)(As + (aoff[i] ^ kx));
                #pragma unroll
                for (int j = 0; j < 4; j++)
                    acc[i][j] = __builtin_amdgcn_mfma_f32_16x16x32_bf16(af, bfr[j], acc[i][j], 0, 0, 0);
            }
        }
    }

    // epilogue. C/D layout: col = lane&15, row = 4*(lane>>4)+reg
    const int c_l = lane & 15;
    const int r_l = (lane >> 4) << 2;
    #pragma unroll
    for (int j = 0; j < 4; j++) {
        const int fcol = n0 + wc * 64 + j * 16 + c_l;
        float bvv;
        if constexpr (EPI == 3) bvv = (fcol < HID) ? bias[fcol] : bias2[fcol - HID];
        else                    bvv = bias[fcol];
        float s2l = 0.f, s6l = 0.f;
        #pragma unroll
        for (int i = 0; i < 4; i++) {
            const int frow = m0 + wr * 64 + i * 16 + r_l;
            #pragma unroll
            for (int r = 0; r < 4; r++) {
                float v = acc[i][j][r] + bvv;
                if constexpr (EPI == 1) {
                    __builtin_nontemporal_store(f2bf16u(gelu_tanh(v)),
                        (unsigned short*)outp + (size_t)(frow + r) * Np + fcol);
                } else if constexpr (EPI == 2) {
                    const size_t off2 = (size_t)(frow + r) * Np + fcol;
                    const int bb = (r0 + frow + r) >> 10;
                    ((float*)outp)[off2] = resid[off2] + gate[(size_t)bb * MODW + fcol] * v;
                } else {  // EPI 3
                    unsigned short bf = f2bf16u(v);
                    if (fcol < HID) ((unsigned short*)outp)[(size_t)(frow + r) * HID + fcol] = bf;
                    else            ((unsigned short*)out2)[(size_t)(frow + r) * (2*KVC) + (fcol - HID)] = bf;
                    if (fcol < HID + KVC) {
                        float rv = fmaxf(v, 0.f);
                        float v2 = rv * rv;
                        s2l += v2;
                        s6l += v2 * v2 * v2;
                    }
                }
            }
        }
        if constexpr (EPI == 3) {
            if (fcol < HID + KVC) {
                s2l += __shfl_down(s2l, 32, 64); s2l += __shfl_down(s2l, 16, 64);
                s6l += __shfl_down(s6l, 32, 64); s6l += __shfl_down(s6l, 16, 64);
                if (lane < 16) {
                    const int slot = (fcol < HID) ? (fcol / 96) : (12 + (fcol - HID) / 96);
                    atomicAdd(&sb2[slot], s2l);
                    atomicAdd(&sb6[slot], s6l);
                }
            }
        }
    }
    if constexpr (EPI == 3) {
        __syncthreads();
        if (tid < 16) {
            const int b = (r0 + m0) >> 10;
            if (tid < 12) {
                atomicAdd(&qsn[(b * HEADS + tid) * 2],     sb2[tid]);
                atomicAdd(&qsn[(b * HEADS + tid) * 2 + 1], sb6[tid]);
            } else {
                atomicAdd(&ksn[(b * KVH + tid - 12) * 2],     sb2[tid]);
                atomicAdd(&ksn[(b * KVH + tid - 12) * 2 + 1], sb6[tid]);
            }
        }
    }
}

// ---------------- depthwise 3x3 conv (bf16 in): 4 channels/thread ----------------
__global__ __launch_bounds__(256) void k_dwconv(const unsigned short* __restrict__ kvl,
                                                const float* __restrict__ w,
                                                const float* __restrict__ bias,
                                                unsigned short* __restrict__ vd) {
    const int idx = blockIdx.x * 256 + threadIdx.x;   // < CROWS*96
    const int c4 = idx % 96;
    const int bn = idx / 96;
    const int n = bn & 1023;
    const int b = bn >> 10;
    const int y = n >> 5, xx = n & 31;
    float4 acc = *(const float4*)(bias + c4 * 4);
    #pragma unroll
    for (int dy = -1; dy <= 1; dy++) {
        const int yy = y + dy;
        if ((unsigned)yy > 31u) continue;
        #pragma unroll
        for (int dx = -1; dx <= 1; dx++) {
            const int xc = xx + dx;
            if ((unsigned)xc > 31u) continue;
            uint2 u = *(const uint2*)(kvl + ((size_t)b * SEQ + yy * 32 + xc) * (2*KVC) + KVC + c4 * 4);
            const int t = (dy + 1) * 3 + (dx + 1);
            acc.x += w[(c4 * 4 + 0) * 9 + t] * bfu2f((unsigned short)(u.x & 0xffff));
            acc.y += w[(c4 * 4 + 1) * 9 + t] * bfu2f((unsigned short)(u.x >> 16));
            acc.z += w[(c4 * 4 + 2) * 9 + t] * bfu2f((unsigned short)(u.y & 0xffff));
            acc.w += w[(c4 * 4 + 3) * 9 + t] * bfu2f((unsigned short)(u.y >> 16));
        }
    }
    uint2 o; o.x = pack2(acc.x, acc.y); o.y = pack2(acc.z, acc.w);
    *(uint2*)(vd + (size_t)idx * 4) = o;
}

// ---------------- kvmat partials: relu(k)^3 ^T @ v over 128-row chunk ----------------
__global__ __launch_bounds__(256) void k_kvpart(const unsigned short* __restrict__ kvl,
                                                float* __restrict__ kvmp) {
    const int chunk = blockIdx.x & 7;
    const int bh = blockIdx.x >> 3;
    const int b = bh >> 2, h = bh & 3;
    __shared__ float Ks[16][96], Vs[16][96];
    float acc[6][6];
    #pragma unroll
    for (int i = 0; i < 6; i++)
        #pragma unroll
        for (int j = 0; j < 6; j++) acc[i][j] = 0.f;
    const int ti = threadIdx.x >> 4, tj = threadIdx.x & 15;
    const unsigned short* kbase = kvl + ((size_t)b * SEQ + chunk * 128) * (2*KVC) + h * HD;
    for (int n0 = 0; n0 < 128; n0 += 16) {
        __syncthreads();
        for (int i = threadIdx.x; i < 384; i += 256) {
            const int kv = (i >= 192);
            const int j = i - kv * 192;
            const int row = j / 12, c = j % 12;
            uint4 u = *(const uint4*)(kbase + (size_t)(n0 + row) * (2*KVC) + kv * KVC + c * 8);
            const unsigned short* e = (const unsigned short*)&u;
            if (!kv) {
                #pragma unroll
                for (int q = 0; q < 8; q++) {
                    float r = fmaxf(bfu2f(e[q]), 0.f);
                    Ks[row][c * 8 + q] = r * r * r;
                }
            } else {
                #pragma unroll
                for (int q = 0; q < 8; q++) Vs[row][c * 8 + q] = bfu2f(e[q]);
            }
        }
        __syncthreads();
        for (int nn = 0; nn < 16; nn++) {
            float av[6], bv[6];
            #pragma unroll
            for (int i = 0; i < 6; i++) av[i] = Ks[nn][ti * 6 + i];
            #pragma unroll
            for (int j = 0; j < 6; j++) bv[j] = Vs[nn][tj * 6 + j];
            #pragma unroll
            for (int i = 0; i < 6; i++)
                #pragma unroll
                for (int j = 0; j < 6; j++) acc[i][j] += av[i] * bv[j];
        }
    }
    float* out = kvmp + ((size_t)bh * 8 + chunk) * 9216;
    #pragma unroll
    for (int i = 0; i < 6; i++)
        #pragma unroll
        for (int j = 0; j < 6; j++)
            out[(size_t)(ti * 6 + i) * 96 + tj * 6 + j] = acc[i][j];
}

// ---------------- kvmat reduce: sum 8 partials, apply k-scale (inline from ksn), emit TRANSPOSED bf16 ----------------
__global__ __launch_bounds__(256) void k_kvred(const float* __restrict__ kvmp,
                                               const float* __restrict__ ksn,
                                               unsigned short* __restrict__ kvmT, int b0) {
    const int idx = blockIdx.x * 256 + threadIdx.x;   // < CB*4*9216
    const int bh = idx / 9216;
    const int i  = idx % 9216;                        // i = d*96 + e
    float s = 0.f;
    #pragma unroll
    for (int c = 0; c < 8; c++) s += kvmp[((size_t)bh * 8 + c) * 9216 + i];
    const int gh = (b0 + (bh >> 2)) * KVH + (bh & 3);
    const float s2 = ksn[gh * 2], s6 = ksn[gh * 2 + 1];
    const float apn = (s6 == 0.f) ? 1e-12f : sqrtf(s6);
    s *= sqrtf(s2) / apn;
    const int d = i / 96, e = i % 96;
    kvmT[(size_t)bh * 9216 + e * 96 + d] = f2bf16u(s);
}

// ---------------- o = focused(q) @ kvmat[h%4] + vd[h%4] -- MFMA version ----------------
__global__ __launch_bounds__(256) void k_ogemm(const unsigned short* __restrict__ ql,
                                               const float* __restrict__ qsn,
                                               const unsigned short* __restrict__ kvmT,
                                               const unsigned short* __restrict__ vd,
                                               unsigned short* __restrict__ obuf,
                                               int b0) {
    const int rc = blockIdx.x;   // 0..7 row chunks of 128
    const int h  = blockIdx.y;   // 0..11
    const int b  = blockIdx.z;   // local batch
    const int kvh = h & 3;
    __shared__ unsigned short Qs[128][104];
    __shared__ unsigned short Ms[96][104];
    const int tid = threadIdx.x;
    const int gq = (b0 + b) * HEADS + h;
    const float qs2 = qsn[gq * 2], qs6 = qsn[gq * 2 + 1];
    const float qs = sqrtf(qs2) / ((qs6 == 0.f) ? 1e-12f : sqrtf(qs6));
    const unsigned short* mt = kvmT + (size_t)(b * KVH + kvh) * 9216;
    for (int i = tid; i < 1152; i += 256) {
        const int row = i / 12, c = i % 12;
        *(uint4*)&Ms[row][c * 8] = *(const uint4*)(mt + row * 96 + c * 8);
    }
    const unsigned short* qb = ql + ((size_t)(b * SEQ + rc * 128)) * HID + h * HD;
    for (int i = tid; i < 1536; i += 256) {
        const int row = i / 12, c = i % 12;
        uint4 u = *(const uint4*)(qb + (size_t)row * HID + c * 8);
        const unsigned short* e = (const unsigned short*)&u;
        unsigned short o8[8];
        #pragma unroll
        for (int q = 0; q < 8; q++) {
            float a = fmaxf(bfu2f(e[q]), 0.f);
            o8[q] = f2bf16u(qs * a * a * a);
        }
        *(uint4*)&Qs[row][c * 8] = *(uint4*)o8;
    }
    __syncthreads();
    const int wave = tid >> 6, lane = tid & 63;
    const int lo = lane & 15, hi = lane >> 4;
    f32x4 acc[2][6];
    #pragma unroll
    for (int m = 0; m < 2; m++)
        #pragma unroll
        for (int n = 0; n < 6; n++) acc[m][n] = (f32x4){0.f, 0.f, 0.f, 0.f};
    #pragma unroll
    for (int ks = 0; ks < 3; ks++) {
        short8 af[2], bf[6];
        #pragma unroll
        for (int m = 0; m < 2; m++)
            af[m] = *(const short8*)&Qs[wave * 32 + m * 16 + lo][ks * 32 + 8 * hi];
        #pragma unroll
        for (int n = 0; n < 6; n++)
            bf[n] = *(const short8*)&Ms[n * 16 + lo][ks * 32 + 8 * hi];
        #pragma unroll
        for (int m = 0; m < 2; m++)
            #pragma unroll
            for (int n = 0; n < 6; n++)
                acc[m][n] = __builtin_amdgcn_mfma_f32_16x16x32_bf16(af[m], bf[n], acc[m][n], 0, 0, 0);
    }
    #pragma unroll
    for (int m = 0; m < 2; m++) {
        #pragma unroll
        for (int n = 0; n < 6; n++) {
            const int e = n * 16 + lo;
            #pragma unroll
            for (int r = 0; r < 4; r++) {
                const size_t gr = (size_t)b * SEQ + rc * 128 + wave * 32 + m * 16 + 4 * hi + r;
                float v = acc[m][n][r] + bfu2f(vd[gr * KVC + kvh * HD + e]);
                obuf[gr * HID + h * HD + e] = f2bf16u(v);
            }
        }
    }
}

// ---------------- fixed workspace layout ----------------
constexpr size_t WQKV_OFF = 0;                                    // [1920][1152] bf16
constexpr size_t WPT_OFF  = WQKV_OFF + (size_t)1920*1152*2;       // [1152][1152] bf16
constexpr size_t W1T_OFF  = WPT_OFF  + (size_t)1152*1152*2;       // [4608][1152] bf16
constexpr size_t W2T_OFF  = W1T_OFF  + (size_t)4608*1152*2;       // [1152][4608] bf16
constexpr size_t MOD_OFF  = W2T_OFF  + (size_t)1152*4608*2;       // 32*6912 f32
constexpr size_t QSN_OFF  = MOD_OFF  + (size_t)BB*MODW*4;         // 32*12*2 f32 (s2,s6)
constexpr size_t KSN_OFF  = QSN_OFF  + (size_t)BB*HEADS*2*4;      // 32*4*2 f32
constexpr size_t DYN_OFF  = KSN_OFF  + (size_t)BB*KVH*2*4;        // chunked scratch

extern "C" void kernel_launch(void* const* d_in, const int* in_sizes, int n_in,
                              void* d_out, int out_size, void* d_ws, size_t ws_size,
                              hipStream_t stream) {
    (void)in_sizes; (void)n_in; (void)out_size;

    const float* x       = (const float*)d_in[0];
    const float* cvec    = (const float*)d_in[1];
    const float* wq_w    = (const float*)d_in[2];
    const float* wq_b    = (const float*)d_in[3];
    const float* wkv_w   = (const float*)d_in[4];
    const float* wkv_b   = (const float*)d_in[5];
    const float* dwc_w   = (const float*)d_in[6];
    const float* dwc_b   = (const float*)d_in[7];
    const float* proj_w  = (const float*)d_in[8];
    const float* proj_b  = (const float*)d_in[9];
    const float* adaln_w = (const float*)d_in[10];
    const float* adaln_b = (const float*)d_in[11];
    const float* mlp_w1  = (const float*)d_in[12];
    const float* mlp_b1  = (const float*)d_in[13];
    const float* mlp_w2  = (const float*)d_in[14];
    const float* mlp_b2  = (const float*)d_in[15];

    // ---- adaptive chunk size ----
    int CB = 0;
    for (int cb = 32; cb >= 1; cb >>= 1) {
        size_t rows = (size_t)cb * 1024;
        size_t attn = rows * (1152*2 + 1152*2 + 768*2 + 384*2 + 1152*2)
                    + (size_t)cb * (4*8*9216*4 /*KVMp*/ + 4*9216*2 /*KVMT*/);
        size_t mlp  = rows * (1152*2 + 4608*2);
        size_t need = DYN_OFF + (attn > mlp ? attn : mlp);
        if (need <= ws_size) { CB = cb; break; }
    }
    if (CB == 0) return;
    const size_t CROWS = (size_t)CB * 1024;

    char* ws = (char*)d_ws;
    unsigned short* WQKV = (unsigned short*)(ws + WQKV_OFF);
    unsigned short* WPT  = (unsigned short*)(ws + WPT_OFF);
    unsigned short* W1T  = (unsigned short*)(ws + W1T_OFF);
    unsigned short* W2T  = (unsigned short*)(ws + W2T_OFF);
    float*          MODp = (float*)(ws + MOD_OFF);
    float*          QSN  = (float*)(ws + QSN_OFF);
    float*          KSN  = (float*)(ws + KSN_OFF);
    char* dyn = ws + DYN_OFF;
    unsigned short* XMc  = (unsigned short*)dyn;
    unsigned short* QLc  = (unsigned short*)(dyn + CROWS * 1152 * 2);
    unsigned short* KVLc = (unsigned short*)((char*)QLc + CROWS * 1152 * 2);
    float*          KVMp = (float*)((char*)KVLc + CROWS * 768 * 2);
    unsigned short* KVMT = (unsigned short*)((char*)KVMp + (size_t)CB * 4 * 8 * 9216 * 4);
    unsigned short* VDc  = (unsigned short*)((char*)KVMT + (size_t)CB * 4 * 9216 * 2);
    unsigned short* OBc  = (unsigned short*)((char*)VDc + CROWS * 384 * 2);
    unsigned short* XM2  = (unsigned short*)dyn;
    unsigned short* Hc   = (unsigned short*)(dyn + CROWS * 1152 * 2);
    float*          OUT  = (float*)d_out;

    dim3 tb(32, 8);
    k_transpose_bf16<<<dim3(36, 36),  tb, 0, stream>>>(wq_w,   WQKV,             1152, 1152);
    k_transpose_bf16<<<dim3(36, 24),  tb, 0, stream>>>(wkv_w,  WQKV + 1152*1152, 1152, 768);
    k_transpose_bf16<<<dim3(36, 36),  tb, 0, stream>>>(proj_w, WPT,              1152, 1152);
    k_transpose_bf16<<<dim3(36, 144), tb, 0, stream>>>(mlp_w1, W1T,              1152, 4608);
    k_transpose_bf16<<<dim3(144, 36), tb, 0, stream>>>(mlp_w2, W2T,              4608, 1152);

    k_mod<<<dim3(27, 4), 256, 0, stream>>>(cvec, adaln_w, adaln_b, MODp);
    hipMemsetAsync(ws + QSN_OFF, 0, (size_t)(BB*HEADS*2 + BB*KVH*2) * 4, stream);

    const int MB = (int)(CROWS >> 7);      // 128-row M blocks per chunk
    const int GM = MB < 16 ? MB : 16;

    // --- attention branch, chunked over batches ---
    for (int b0 = 0; b0 < BB; b0 += CB) {
        const int r0 = b0 << 10;
        const float* xch = x + (size_t)r0 * HID;
        k_ln_mod<<<(int)CROWS, 256, 0, stream>>>(xch, MODp, 0, 1, XMc, r0);
        k_gemm_bt<3><<<15 * MB, 256, 0, stream>>>(XMc, WQKV, wq_b, wkv_b, QLc, KVLc,
                                                  nullptr, nullptr, QSN, KSN,
                                                  0, 1152, r0, MB, GM, 5, 8, 1);
        k_dwconv<<<(int)(CROWS * 96 / 256), 256, 0, stream>>>(KVLc, dwc_w, dwc_b, VDc);
        k_kvpart<<<CB * 4 * 8, 256, 0, stream>>>(KVLc, KVMp);
        k_kvred<<<CB * 144, 256, 0, stream>>>(KVMp, KSN, KVMT, b0);
        k_ogemm<<<dim3(8, HEADS, CB), 256, 0, stream>>>(QLc, QSN, KVMT, VDc, OBc, b0);
        k_gemm_bt<2><<<9 * MB, 256, 0, stream>>>(OBc, WPT, proj_b, nullptr, OUT + (size_t)r0 * HID, nullptr,
                                                 xch, MODp + 2 * HID, nullptr, nullptr,
                                                 1152, 1152, r0, MB, GM, 9, 8, 1);
    }

    // --- MLP branch, chunked over rows (d_out now holds x1 = x + gate*attn) ---
    for (int r0 = 0; r0 < ROWS; r0 += (int)CROWS) {
        float* x1ch = OUT + (size_t)r0 * HID;
        k_ln_mod<<<(int)CROWS, 256, 0, stream>>>(x1ch, MODp, 3, 4, XM2, r0);
        k_gemm_bt<1><<<36 * MB, 256, 0, stream>>>(XM2, W1T, mlp_b1, nullptr, Hc, nullptr,
                                                  nullptr, nullptr, nullptr, nullptr,
                                                  4608, 1152, 0, MB, GM, 12, 2, 4);
        k_gemm_bt<2><<<9 * MB, 256, 0, stream>>>(Hc, W2T, mlp_b2, nullptr, x1ch, nullptr,
                                                 x1ch, MODp + 5 * HID, nullptr, nullptr,
                                                 1152, 4608, r0, MB, GM, 9, 8, 1);
    }
}